// Round 13
// baseline (61.343 us; speedup 1.0000x reference)
//
#include <hip/hip_runtime.h>
#include <hip/hip_bf16.h>

typedef __attribute__((ext_vector_type(8))) short short8;
typedef __attribute__((ext_vector_type(4))) float f32x4;

#define NB 8
#define LQ 2048
#define LK 2048
#define DIN 1024
#define MROWS (NB * LQ)   // 16384

static constexpr float KSCALE = 0.022097086912079608f; // 1/sqrt(2048)

__device__ __forceinline__ ushort f2bf(float f) {
    union { float f; unsigned int u; } v; v.f = f;
    unsigned int r = v.u + 0x7FFFu + ((v.u >> 16) & 1u);   // RNE
    return (ushort)(r >> 16);
}
__device__ __forceinline__ float bf2f(ushort u) {
    union { unsigned int u; float f; } v; v.u = ((unsigned int)u) << 16;
    return v.f;
}
__device__ __forceinline__ unsigned pk2(float lo, float hi) {
    __hip_bfloat162 h = __float22bfloat162_rn(float2{lo, hi});   // v_cvt_pk_bf16_f32
    union { __hip_bfloat162 h; unsigned u; } c; c.h = h; return c.u;
}
__device__ __forceinline__ short8 cvt8(float4 lo, float4 hi) {
    union { short8 s; unsigned u[4]; } r;
    r.u[0] = pk2(lo.x, lo.y);
    r.u[1] = pk2(lo.z, lo.w);
    r.u[2] = pk2(hi.x, hi.y);
    r.u[3] = pk2(hi.z, hi.w);
    return r.s;
}

// async global->LDS, 16B per lane; LDS dst is wave-uniform base + lane*16
__device__ __forceinline__ void gl16(const void* g, void* l) {
    __builtin_amdgcn_global_load_lds(
        (const __attribute__((address_space(1))) void*)g,
        (__attribute__((address_space(3))) void*)l, 16, 0, 0);
}

// ---------------------------------------------------------------------------
// prep: Wt[p][n][k] = bf16(W_p[k][n])  (transpose+convert, LDS tiled)
// ---------------------------------------------------------------------------
__global__ __launch_bounds__(256) void prep_kernel(
    const float* __restrict__ Wq, const float* __restrict__ Wk,
    const float* __restrict__ Wv, ushort* __restrict__ Wt)
{
    const float* W = (blockIdx.z == 0) ? Wq : (blockIdx.z == 1) ? Wk : Wv;
    ushort* O = Wt + (size_t)blockIdx.z * 128 * 1024;
    const int k0 = blockIdx.x * 64, n0 = blockIdx.y * 64;
    __shared__ float tile[64][65];
    const int t = threadIdx.x;
    {
        const int r = t >> 4, c = (t & 15) * 4;
        #pragma unroll
        for (int i = 0; i < 4; ++i) {
            float4 v = *(const float4*)&W[(size_t)(k0 + r + i * 16) * 128 + n0 + c];
            tile[r + i * 16][c + 0] = v.x; tile[r + i * 16][c + 1] = v.y;
            tile[r + i * 16][c + 2] = v.z; tile[r + i * 16][c + 3] = v.w;
        }
    }
    __syncthreads();
    {
        const int n = t >> 2, kc = (t & 3) * 16;
        ushort tmp[16];
        #pragma unroll
        for (int j = 0; j < 16; ++j) tmp[j] = f2bf(tile[kc + j][n]);
        *(uint4*)&O[(size_t)(n0 + n) * 1024 + k0 + kc]     = *(uint4*)&tmp[0];
        *(uint4*)&O[(size_t)(n0 + n) * 1024 + k0 + kc + 8] = *(uint4*)&tmp[8];
    }
}

// ---------------------------------------------------------------------------
// proj: Y = bf16(relu(X[16384,1024] @ W + b))
// 128x128 tile (was 64x128): halves the W re-fetch (384->288 MB total
// staged) — R12 analysis showed proj is BW-bound on STAGED bytes at the
// warm-L3 ceiling (~9 TB/s), not latency/TLP-bound. Same proven ring:
// 3-deep, BK=32, counted vmcnt FENCE(3), raw s_barrier. 8 waves (512 thr),
// wave = 32x64 sub-tile (2 A-frags, 8 MFMA/step). LDS 72 KB -> 2 blocks/CU.
// Grid (128,3) = 384 blocks, all co-resident. Epilogue: q row-major;
// k/v transposed [e][16384] for the MFMA-ktv consumer (R12 scheme).
// ---------------------------------------------------------------------------
__global__ __launch_bounds__(512, 4) void proj_kernel(
    const float* __restrict__ Xq, const float* __restrict__ bq,
    const float* __restrict__ Xk, const float* __restrict__ bk,
    const float* __restrict__ Xv, const float* __restrict__ bv,
    const ushort* __restrict__ Wt,
    ushort* __restrict__ qp, ushort* __restrict__ kpT, ushort* __restrict__ vpT)
{
    const int p = blockIdx.y;
    const float* X; const float* bias; ushort* Y;
    if (p == 0)      { X = Xq; bias = bq; Y = qp; }
    else if (p == 1) { X = Xk; bias = bk; Y = kpT; }
    else             { X = Xv; bias = bv; Y = vpT; }
    const ushort* W = Wt + (size_t)p * 131072;

    __shared__ __align__(16) float  As[3 * 4096];    // 48 KB: 3 slots 128x32 fp32
    __shared__ __align__(16) ushort Bs[3 * 4096];    // 24 KB: 3 slots 128x32 bf16

    const int tid  = threadIdx.x;
    const int lane = tid & 63;
    const int w    = tid >> 6;          // 0..7
    const int wr   = (w >> 1) * 32;     // wave row base: 0,32,64,96
    const int wc   = (w & 1) * 64;      // wave col base: 0,64
    const int row0 = blockIdx.x * 128;

    // ---- staging sources (inverse-swizzled per lane; R6 formula family) ----
    // A: wave w stages rows [w*16, w*16+16) via 2 gl16 (rows +0 / +8)
    const int rA = w * 16 + (lane >> 3);
    const int cA = (lane & 7) ^ (lane >> 3);            // row&7 == lane>>3
    const float* gA  = X + (size_t)(row0 + rA) * DIN + cA * 4;
    const float* gA2 = gA + (size_t)8 * DIN;            // (+8 rows, same &7)
    // B: wave w stages superrows [w*8, w*8+8) (superrow = 2 n-rows x 32 bf16)
    const int sB = w * 8 + (lane >> 3);
    const int cB = (lane & 7) ^ (lane >> 3);
    const int nB = 2 * sB + (cB >> 2);
    const ushort* gB = W + (size_t)nB * DIN + (cB & 3) * 8;

    // ---- fragment read offsets (swizzled; R6 family) ----
    const int col = lane & 15;
    const int kg  = (lane >> 4) * 8;
    const int c0  = kg >> 2;
    const int bc  = kg >> 3;
    const int ra  = wr + col;
    const int axr = ra & 7;
    const int aLo = ra * 32 + ((c0 ^ axr) << 2);        // mi=1: +512
    const int aHi = ra * 32 + (((c0 + 1) ^ axr) << 2);
    const int nb0 = wc + col;
    const int bO  = (nb0 >> 1) * 64 +
                    (((((nb0 & 1) << 2) | bc) ^ ((nb0 >> 1) & 7)) << 3);

    f32x4 acc[2][4];
    #pragma unroll
    for (int mi = 0; mi < 2; ++mi)
        #pragma unroll
        for (int ni = 0; ni < 4; ++ni)
            acc[mi][ni] = (f32x4){0.f, 0.f, 0.f, 0.f};

#define STAGE(s_, t_) do {                                                    \
    gl16(gA  + (t_) * 32, &As[(s_) * 4096 + w * 512]);                        \
    gl16(gA2 + (t_) * 32, &As[(s_) * 4096 + w * 512 + 256]);                  \
    gl16(gB  + (t_) * 32, &Bs[(s_) * 4096 + w * 512]);                        \
} while (0)

#define STEP(s_) do {                                                         \
    float4 lo0 = *(const float4*)&As[(s_) * 4096 + aLo];                      \
    float4 hi0 = *(const float4*)&As[(s_) * 4096 + aHi];                      \
    float4 lo1 = *(const float4*)&As[(s_) * 4096 + aLo + 512];                \
    float4 hi1 = *(const float4*)&As[(s_) * 4096 + aHi + 512];                \
    short8 bf0 = *(const short8*)&Bs[(s_) * 4096 + bO];                       \
    short8 bf1 = *(const short8*)&Bs[(s_) * 4096 + bO + 512];                 \
    short8 bf2 = *(const short8*)&Bs[(s_) * 4096 + bO + 1024];                \
    short8 bf3 = *(const short8*)&Bs[(s_) * 4096 + bO + 1536];                \
    short8 af0 = cvt8(lo0, hi0);                                              \
    short8 af1 = cvt8(lo1, hi1);                                              \
    acc[0][0] = __builtin_amdgcn_mfma_f32_16x16x32_bf16(af0, bf0, acc[0][0], 0, 0, 0); \
    acc[1][0] = __builtin_amdgcn_mfma_f32_16x16x32_bf16(af1, bf0, acc[1][0], 0, 0, 0); \
    acc[0][1] = __builtin_amdgcn_mfma_f32_16x16x32_bf16(af0, bf1, acc[0][1], 0, 0, 0); \
    acc[1][1] = __builtin_amdgcn_mfma_f32_16x16x32_bf16(af1, bf1, acc[1][1], 0, 0, 0); \
    acc[0][2] = __builtin_amdgcn_mfma_f32_16x16x32_bf16(af0, bf2, acc[0][2], 0, 0, 0); \
    acc[1][2] = __builtin_amdgcn_mfma_f32_16x16x32_bf16(af1, bf2, acc[1][2], 0, 0, 0); \
    acc[0][3] = __builtin_amdgcn_mfma_f32_16x16x32_bf16(af0, bf3, acc[0][3], 0, 0, 0); \
    acc[1][3] = __builtin_amdgcn_mfma_f32_16x16x32_bf16(af1, bf3, acc[1][3], 0, 0, 0); \
} while (0)

#define FENCE(n_) do {                                                        \
    asm volatile("s_waitcnt vmcnt(" #n_ ")" ::: "memory");                    \
    __builtin_amdgcn_sched_barrier(0);                                        \
    __builtin_amdgcn_s_barrier();                                             \
    __builtin_amdgcn_sched_barrier(0);                                        \
} while (0)

    STAGE(0, 0);
    STAGE(1, 1);
    FENCE(3);

    #pragma unroll 1
    for (int t = 0; t < 30; t += 3) {
        STAGE(2, t + 2); STEP(0); FENCE(3);
        STAGE(0, t + 3); STEP(1); FENCE(3);
        STAGE(1, t + 4); STEP(2); FENCE(3);
    }
    STEP(0);            // t=30 (stage complete per last in-loop FENCE)
    FENCE(0);           // stage 31 complete
    STEP(1);            // t=31
    __syncthreads();    // all ring reads done; LDS free for Ys reuse

#undef STAGE
#undef STEP
#undef FENCE

    float bb[4];
    #pragma unroll
    for (int ni = 0; ni < 4; ++ni) bb[ni] = bias[wc + ni * 16 + col];

    ushort* Ys = (ushort*)As;           // 128x128 bf16 = 32 KB (in 48 KB ring)
    const int orow4 = (lane >> 4) * 4;
    #pragma unroll
    for (int mi = 0; mi < 2; ++mi)
        #pragma unroll
        for (int ni = 0; ni < 4; ++ni)
            #pragma unroll
            for (int j = 0; j < 4; ++j) {
                float v = fmaxf(acc[mi][ni][j] + bb[ni], 0.f);
                const int rl = wr + mi * 16 + orow4 + j;
                const int cl = wc + ni * 16 + col;
                Ys[(rl * 128 + cl) ^ ((rl & 15) << 3)] = f2bf(v);
            }
    __syncthreads();

    if (p == 0) {
        // row-major write (qm reads q rows): 128 rows x 128 cols
        const int r = tid >> 2, c = (tid & 3) * 32;
        const int swz = (r & 15) << 3;
        ushort* Yg = Y + (size_t)(row0 + r) * 128 + c;
        #pragma unroll
        for (int j = 0; j < 4; ++j)
            *(uint4*)&Yg[j * 8] = *(const uint4*)&Ys[(r * 128 + c + j * 8) ^ swz];
    } else {
        // transposed write: Y[e][16384]; thread = (col e, 32-row group)
        const int c  = tid >> 2;            // 0..127
        const int rq = (tid & 3) * 32;      // 0,32,64,96
        ushort tmp[32];
        #pragma unroll
        for (int j = 0; j < 32; ++j) {
            const int r = rq + j;
            tmp[j] = Ys[(r * 128 + c) ^ ((r & 15) << 3)];
        }
        ushort* Yg = Y + (size_t)c * MROWS + row0 + rq;
        #pragma unroll
        for (int j = 0; j < 4; ++j)
            *(uint4*)&Yg[j * 8] = *(const uint4*)&tmp[j * 8];
    }
}

// ---------------------------------------------------------------------------
// ktv (MFMA): part[b*16+c][v][e] = sum_{r in chunk c} v[r][v]*k[r][e]
// ---------------------------------------------------------------------------
__global__ __launch_bounds__(256) void ktv_kernel(
    const ushort* __restrict__ kpT, const ushort* __restrict__ vpT,
    ushort* __restrict__ part)
{
    const int c = blockIdx.x;           // r-chunk 0..15 (128 rows)
    const int b = blockIdx.y;
    const size_t rbase = (size_t)b * LK + c * 128;

    __shared__ __align__(16) ushort Ks[128 * 128];   // 32 KB
    __shared__ __align__(16) ushort Vs[128 * 128];   // 32 KB

    const int t = threadIdx.x;
    {
        const int e = t >> 1, half = (t & 1) * 64;
        const int swz = (e & 15) << 3;
        const ushort* sk = kpT + (size_t)e * MROWS + rbase + half;
        const ushort* sv = vpT + (size_t)e * MROWS + rbase + half;
        #pragma unroll
        for (int j = 0; j < 8; ++j) {
            *(uint4*)&Ks[(e * 128 + half + j * 8) ^ swz] = *(const uint4*)&sk[j * 8];
            *(uint4*)&Vs[(e * 128 + half + j * 8) ^ swz] = *(const uint4*)&sv[j * 8];
        }
    }
    __syncthreads();

    const int lane = t & 63;
    const int w    = t >> 6;
    const int we   = w * 32;            // wave's e-rows
    const int col  = lane & 15;
    const int kgrp = (lane >> 4) * 8;
    const int fswz = col << 3;

    f32x4 acc[2][8];
    #pragma unroll
    for (int mi = 0; mi < 2; ++mi)
        #pragma unroll
        for (int ni = 0; ni < 8; ++ni)
            acc[mi][ni] = (f32x4){0.f, 0.f, 0.f, 0.f};

    #pragma unroll
    for (int kk = 0; kk < 4; ++kk) {
        const int kb = kk * 32 + kgrp;
        short8 af[2], bfv[8];
        #pragma unroll
        for (int mi = 0; mi < 2; ++mi)
            af[mi] = *(const short8*)&Ks[((we + mi * 16 + col) * 128 + kb) ^ fswz];
        #pragma unroll
        for (int ni = 0; ni < 8; ++ni)
            bfv[ni] = *(const short8*)&Vs[((ni * 16 + col) * 128 + kb) ^ fswz];
        #pragma unroll
        for (int mi = 0; mi < 2; ++mi)
            #pragma unroll
            for (int ni = 0; ni < 8; ++ni)
                acc[mi][ni] = __builtin_amdgcn_mfma_f32_16x16x32_bf16(
                    af[mi], bfv[ni], acc[mi][ni], 0, 0, 0);
    }

    __syncthreads();
    const int orow4 = (lane >> 4) * 4;
    #pragma unroll
    for (int mi = 0; mi < 2; ++mi)
        #pragma unroll
        for (int ni = 0; ni < 8; ++ni)
            #pragma unroll
            for (int j = 0; j < 4; ++j) {
                const int e = we + mi * 16 + orow4 + j;
                const int v = ni * 16 + col;
                Ks[(v * 128 + e) ^ ((v & 15) << 3)] = f2bf(acc[mi][ni][j]);
            }
    __syncthreads();

    ushort* P = part + (size_t)(b * 16 + c) * 16384;
    {
        const int v = t >> 1, half = (t & 1) * 64;
        const int swz = (v & 15) << 3;
        #pragma unroll
        for (int j = 0; j < 8; ++j)
            *(uint4*)&P[v * 128 + half + j * 8] =
                *(const uint4*)&Ks[(v * 128 + half + j * 8) ^ swz];
    }
}

// ---------------------------------------------------------------------------
// reduce: Mt[b][v*128+e] = bf16(KSCALE * sum_{c<16} part[b*16+c][v*128+e])
// ---------------------------------------------------------------------------
__global__ __launch_bounds__(256) void reduce_kernel(
    const ushort* __restrict__ part, ushort* __restrict__ Mt)
{
    const int g = blockIdx.x * 256 + threadIdx.x;
    const int b = g >> 14, idx = g & 16383;
    const ushort* P = part + (size_t)b * 16 * 16384 + idx;
    float s = 0.f;
    #pragma unroll
    for (int c = 0; c < 16; ++c) s += bf2f(P[(size_t)c * 16384]);
    Mt[g] = f2bf(s * KSCALE);
}

// ---------------------------------------------------------------------------
// qm: out[row][v] = sum_e qp[row][e] * Mt[b][v][e]
// ---------------------------------------------------------------------------
__global__ __launch_bounds__(256) void qm_kernel(
    const ushort* __restrict__ qp, const ushort* __restrict__ Mt,
    float* __restrict__ out)
{
    const int row0 = blockIdx.x * 64;
    const int b = row0 >> 11;
    const ushort* Q = qp + (size_t)row0 * 128;
    const ushort* M = Mt + (size_t)b * 16384;

    __shared__ __align__(16) ushort As[64 * 128];
    __shared__ __align__(16) ushort Bs[128 * 128];

    const int t = threadIdx.x;
    {
        const int r = t >> 2, cc = (t & 3) * 32;
        const int swz = (r & 15) << 3;
        #pragma unroll
        for (int j = 0; j < 4; ++j)
            *(uint4*)&As[(r * 128 + cc + j * 8) ^ swz] = *(const uint4*)&Q[r * 128 + cc + j * 8];
    }
    {
        const int r = t >> 1, cc = (t & 1) * 64;
        const int swz = (r & 15) << 3;
        #pragma unroll
        for (int j = 0; j < 8; ++j)
            *(uint4*)&Bs[(r * 128 + cc + j * 8) ^ swz] = *(const uint4*)&M[r * 128 + cc + j * 8];
    }
    __syncthreads();

    const int lane = t & 63;
    const int wcol = (t >> 6) * 32;
    const int col  = lane & 15;
    const int kgrp = (lane >> 4) * 8;
    const int fswz = col << 3;

    f32x4 acc[4][2];
    #pragma unroll
    for (int mi = 0; mi < 4; ++mi)
        #pragma unroll
        for (int ni = 0; ni < 2; ++ni)
            acc[mi][ni] = (f32x4){0.f, 0.f, 0.f, 0.f};

    #pragma unroll
    for (int kk = 0; kk < 4; ++kk) {
        const int kb = kk * 32 + kgrp;
        short8 af[4], bfv[2];
        #pragma unroll
        for (int mi = 0; mi < 4; ++mi)
            af[mi] = *(const short8*)&As[((mi * 16 + col) * 128 + kb) ^ fswz];
        #pragma unroll
        for (int ni = 0; ni < 2; ++ni)
            bfv[ni] = *(const short8*)&Bs[((wcol + ni * 16 + col) * 128 + kb) ^ fswz];
        #pragma unroll
        for (int mi = 0; mi < 4; ++mi)
            #pragma unroll
            for (int ni = 0; ni < 2; ++ni)
                acc[mi][ni] = __builtin_amdgcn_mfma_f32_16x16x32_bf16(
                    af[mi], bfv[ni], acc[mi][ni], 0, 0, 0);
    }

    const int orow = (lane >> 4) * 4;
    #pragma unroll
    for (int mi = 0; mi < 4; ++mi)
        #pragma unroll
        for (int ni = 0; ni < 2; ++ni)
            #pragma unroll
            for (int j = 0; j < 4; ++j)
                out[(size_t)(row0 + mi * 16 + orow + j) * 128 + wcol + ni * 16 + col] =
                    acc[mi][ni][j];
}

// ---------------------------------------------------------------------------
extern "C" void kernel_launch(void* const* d_in, const int* in_sizes, int n_in,
                              void* d_out, int out_size, void* d_ws, size_t ws_size,
                              hipStream_t stream)
{
    const float* query = (const float*)d_in[0];
    const float* key   = (const float*)d_in[1];
    const float* value = (const float*)d_in[2];
    const float* Wq    = (const float*)d_in[3];
    const float* bq    = (const float*)d_in[4];
    const float* Wk    = (const float*)d_in[5];
    const float* bk    = (const float*)d_in[6];
    const float* Wv    = (const float*)d_in[7];
    const float* bv    = (const float*)d_in[8];
    float* out = (float*)d_out;

    ushort* qp   = (ushort*)d_ws;                    // 16384*128 bf16
    ushort* kpT  = qp + (size_t)MROWS * 128;         // [128][16384] bf16
    ushort* vpT  = kpT + (size_t)MROWS * 128;        // [128][16384] bf16
    ushort* Wt   = vpT + (size_t)MROWS * 128;        // 3*128*1024 bf16
    ushort* part = Wt + (size_t)3 * 128 * 1024;      // 8*16*16384 bf16 (4 MB)
    ushort* Mt   = part + (size_t)8 * 16 * 16384;    // 8*16384 bf16

    prep_kernel<<<dim3(16, 2, 3), 256, 0, stream>>>(Wq, Wk, Wv, Wt);
    proj_kernel<<<dim3(128, 3), 512, 0, stream>>>(query, bq, key, bk, value, bv,
                                                  Wt, qp, kpT, vpT);
    ktv_kernel<<<dim3(16, NB), 256, 0, stream>>>(kpT, vpT, part);
    reduce_kernel<<<512, 256, 0, stream>>>(part, Mt);
    qm_kernel<<<MROWS / 64, 256, 0, stream>>>(qp, Mt, out);
}

// Round 14
// 58.511 us; speedup vs baseline: 1.0484x; 1.0484x over previous
//
#include <hip/hip_runtime.h>
#include <hip/hip_bf16.h>

typedef __attribute__((ext_vector_type(8))) short short8;
typedef __attribute__((ext_vector_type(4))) float f32x4;

#define NB 8
#define LQ 2048
#define LK 2048
#define DIN 1024
#define MROWS (NB * LQ)   // 16384

static constexpr float KSCALE = 0.022097086912079608f; // 1/sqrt(2048)

__device__ __forceinline__ ushort f2bf(float f) {
    union { float f; unsigned int u; } v; v.f = f;
    unsigned int r = v.u + 0x7FFFu + ((v.u >> 16) & 1u);   // RNE
    return (ushort)(r >> 16);
}
__device__ __forceinline__ float bf2f(ushort u) {
    union { unsigned int u; float f; } v; v.u = ((unsigned int)u) << 16;
    return v.f;
}
__device__ __forceinline__ unsigned pk2(float lo, float hi) {
    __hip_bfloat162 h = __float22bfloat162_rn(float2{lo, hi});   // v_cvt_pk_bf16_f32
    union { __hip_bfloat162 h; unsigned u; } c; c.h = h; return c.u;
}
__device__ __forceinline__ short8 cvt8(float4 lo, float4 hi) {
    union { short8 s; unsigned u[4]; } r;
    r.u[0] = pk2(lo.x, lo.y);
    r.u[1] = pk2(lo.z, lo.w);
    r.u[2] = pk2(hi.x, hi.y);
    r.u[3] = pk2(hi.z, hi.w);
    return r.s;
}

// async global->LDS, 16B per lane; LDS dst is wave-uniform base + lane*16
__device__ __forceinline__ void gl16(const void* g, void* l) {
    __builtin_amdgcn_global_load_lds(
        (const __attribute__((address_space(1))) void*)g,
        (__attribute__((address_space(3))) void*)l, 16, 0, 0);
}

// ---------------------------------------------------------------------------
// prep: Wt[p][n][k] = bf16(W_p[k][n])  (transpose+convert, LDS tiled)
// ---------------------------------------------------------------------------
__global__ __launch_bounds__(256) void prep_kernel(
    const float* __restrict__ Wq, const float* __restrict__ Wk,
    const float* __restrict__ Wv, ushort* __restrict__ Wt)
{
    const float* W = (blockIdx.z == 0) ? Wq : (blockIdx.z == 1) ? Wk : Wv;
    ushort* O = Wt + (size_t)blockIdx.z * 128 * 1024;
    const int k0 = blockIdx.x * 64, n0 = blockIdx.y * 64;
    __shared__ float tile[64][65];
    const int t = threadIdx.x;
    {
        const int r = t >> 4, c = (t & 15) * 4;
        #pragma unroll
        for (int i = 0; i < 4; ++i) {
            float4 v = *(const float4*)&W[(size_t)(k0 + r + i * 16) * 128 + n0 + c];
            tile[r + i * 16][c + 0] = v.x; tile[r + i * 16][c + 1] = v.y;
            tile[r + i * 16][c + 2] = v.z; tile[r + i * 16][c + 3] = v.w;
        }
    }
    __syncthreads();
    {
        const int n = t >> 2, kc = (t & 3) * 16;
        ushort tmp[16];
        #pragma unroll
        for (int j = 0; j < 16; ++j) tmp[j] = f2bf(tile[kc + j][n]);
        *(uint4*)&O[(size_t)(n0 + n) * 1024 + k0 + kc]     = *(uint4*)&tmp[0];
        *(uint4*)&O[(size_t)(n0 + n) * 1024 + k0 + kc + 8] = *(uint4*)&tmp[8];
    }
}

// ---------------------------------------------------------------------------
// proj: R12/R10 measured-best structure VERBATIM. 64x128 tile, 8 waves
// (512 thr), 3-deep ring, BK=32, counted vmcnt FENCE(2), raw s_barrier,
// 48 KB LDS -> 3 blocks/CU (occupancy ~60% — the proven binding lever;
// R11/R13 A/B: dropping to 2 blk/CU loses 4-6 µs regardless of bytes).
// Epilogue: q row-major; k/v transposed [e][16384] for MFMA-ktv.
// ---------------------------------------------------------------------------
__global__ __launch_bounds__(512, 6) void proj_kernel(
    const float* __restrict__ Xq, const float* __restrict__ bq,
    const float* __restrict__ Xk, const float* __restrict__ bk,
    const float* __restrict__ Xv, const float* __restrict__ bv,
    const ushort* __restrict__ Wt,
    ushort* __restrict__ qp, ushort* __restrict__ kpT, ushort* __restrict__ vpT)
{
    const int p = blockIdx.y;
    const float* X; const float* bias; ushort* Y;
    if (p == 0)      { X = Xq; bias = bq; Y = qp; }
    else if (p == 1) { X = Xk; bias = bk; Y = kpT; }
    else             { X = Xv; bias = bv; Y = vpT; }
    const ushort* W = Wt + (size_t)p * 131072;

    __shared__ __align__(16) float  As[3 * 2048];    // 24 KB: 3 slots 64x32 fp32
    __shared__ __align__(16) ushort Bs[3 * 4096];    // 24 KB: 3 slots 128x32 bf16

    const int tid  = threadIdx.x;
    const int lane = tid & 63;
    const int w    = tid >> 6;          // 0..7
    const int wr   = (w >> 1) * 16;     // wave row base: 0,16,32,48
    const int wc   = (w & 1) * 64;      // wave col base: 0,64
    const int row0 = blockIdx.x * 64;

    const int rA = w * 8 + (lane >> 3);
    const int cA = (lane & 7) ^ (lane >> 3);
    const float* gA = X + (size_t)(row0 + rA) * DIN + cA * 4;
    const int sB = w * 8 + (lane >> 3);
    const int cB = (lane & 7) ^ (lane >> 3);
    const int nB = 2 * sB + (cB >> 2);
    const ushort* gB = W + (size_t)nB * DIN + (cB & 3) * 8;

    const int col = lane & 15;
    const int kg  = (lane >> 4) * 8;
    const int c0  = kg >> 2;
    const int bc  = kg >> 3;
    const int ra  = wr + col;
    const int axr = ra & 7;
    const int aLo = ra * 32 + ((c0 ^ axr) << 2);
    const int aHi = ra * 32 + (((c0 + 1) ^ axr) << 2);
    const int nb0 = wc + col;
    const int bO  = (nb0 >> 1) * 64 +
                    (((((nb0 & 1) << 2) | bc) ^ ((nb0 >> 1) & 7)) << 3);

    f32x4 acc[4];
    #pragma unroll
    for (int ni = 0; ni < 4; ++ni) acc[ni] = (f32x4){0.f, 0.f, 0.f, 0.f};

#define STAGE(s_, t_) do {                                                    \
    gl16(gA + (t_) * 32, &As[(s_) * 2048 + w * 256]);                         \
    gl16(gB + (t_) * 32, &Bs[(s_) * 4096 + w * 512]);                         \
} while (0)

#define STEP(s_) do {                                                         \
    float4 lo = *(const float4*)&As[(s_) * 2048 + aLo];                       \
    float4 hi = *(const float4*)&As[(s_) * 2048 + aHi];                       \
    short8 bf0 = *(const short8*)&Bs[(s_) * 4096 + bO];                       \
    short8 bf1 = *(const short8*)&Bs[(s_) * 4096 + bO + 512];                 \
    short8 bf2 = *(const short8*)&Bs[(s_) * 4096 + bO + 1024];                \
    short8 bf3 = *(const short8*)&Bs[(s_) * 4096 + bO + 1536];                \
    short8 af0 = cvt8(lo, hi);                                                \
    acc[0] = __builtin_amdgcn_mfma_f32_16x16x32_bf16(af0, bf0, acc[0], 0, 0, 0); \
    acc[1] = __builtin_amdgcn_mfma_f32_16x16x32_bf16(af0, bf1, acc[1], 0, 0, 0); \
    acc[2] = __builtin_amdgcn_mfma_f32_16x16x32_bf16(af0, bf2, acc[2], 0, 0, 0); \
    acc[3] = __builtin_amdgcn_mfma_f32_16x16x32_bf16(af0, bf3, acc[3], 0, 0, 0); \
} while (0)

#define FENCE(n_) do {                                                        \
    asm volatile("s_waitcnt vmcnt(" #n_ ")" ::: "memory");                    \
    __builtin_amdgcn_sched_barrier(0);                                        \
    __builtin_amdgcn_s_barrier();                                             \
    __builtin_amdgcn_sched_barrier(0);                                        \
} while (0)

    STAGE(0, 0);
    STAGE(1, 1);
    FENCE(2);

    #pragma unroll 1
    for (int t = 0; t < 30; t += 3) {
        STAGE(2, t + 2); STEP(0); FENCE(2);
        STAGE(0, t + 3); STEP(1); FENCE(2);
        STAGE(1, t + 4); STEP(2); FENCE(2);
    }
    STEP(0);            // t=30
    FENCE(0);           // stage 31 complete
    STEP(1);            // t=31
    __syncthreads();    // all ring reads done; LDS free for Ys reuse

#undef STAGE
#undef STEP
#undef FENCE

    float bb[4];
    #pragma unroll
    for (int ni = 0; ni < 4; ++ni) bb[ni] = bias[wc + ni * 16 + col];

    ushort* Ys = (ushort*)As;           // 64x128 bf16 = 16 KB
    const int orow4 = (lane >> 4) * 4;
    #pragma unroll
    for (int ni = 0; ni < 4; ++ni)
        #pragma unroll
        for (int j = 0; j < 4; ++j) {
            float v = fmaxf(acc[ni][j] + bb[ni], 0.f);
            const int rl = wr + orow4 + j;
            const int cl = wc + ni * 16 + col;
            Ys[(rl * 128 + cl) ^ ((rl & 15) << 3)] = f2bf(v);
        }
    __syncthreads();

    if (p == 0) {
        // row-major write (qm reads q rows)
        const int r = tid >> 3, c = (tid & 7) * 16;
        const int swz = (r & 15) << 3;
        ushort* Yg = Y + (size_t)(row0 + r) * 128 + c;
        *(uint4*)&Yg[0] = *(const uint4*)&Ys[(r * 128 + c)     ^ swz];
        *(uint4*)&Yg[8] = *(const uint4*)&Ys[(r * 128 + c + 8) ^ swz];
    } else {
        // transposed write: Y[e][16384]; thread = (col e, 16-row group)
        const int c  = tid >> 2;            // 0..127
        const int rq = (tid & 3) * 16;      // 0,16,32,48
        ushort tmp[16];
        #pragma unroll
        for (int j = 0; j < 16; ++j) {
            const int r = rq + j;
            tmp[j] = Ys[(r * 128 + c) ^ ((r & 15) << 3)];
        }
        ushort* Yg = Y + (size_t)c * MROWS + row0 + rq;
        *(uint4*)&Yg[0] = *(const uint4*)&tmp[0];
        *(uint4*)&Yg[8] = *(const uint4*)&tmp[8];
    }
}

// ---------------------------------------------------------------------------
// ktv (MFMA): part[b*16+c][v][e] = sum_{r in chunk c} v[r][v]*k[r][e]
// ---------------------------------------------------------------------------
__global__ __launch_bounds__(256) void ktv_kernel(
    const ushort* __restrict__ kpT, const ushort* __restrict__ vpT,
    ushort* __restrict__ part)
{
    const int c = blockIdx.x;           // r-chunk 0..15 (128 rows)
    const int b = blockIdx.y;
    const size_t rbase = (size_t)b * LK + c * 128;

    __shared__ __align__(16) ushort Ks[128 * 128];   // 32 KB
    __shared__ __align__(16) ushort Vs[128 * 128];   // 32 KB

    const int t = threadIdx.x;
    {
        const int e = t >> 1, half = (t & 1) * 64;
        const int swz = (e & 15) << 3;
        const ushort* sk = kpT + (size_t)e * MROWS + rbase + half;
        const ushort* sv = vpT + (size_t)e * MROWS + rbase + half;
        #pragma unroll
        for (int j = 0; j < 8; ++j) {
            *(uint4*)&Ks[(e * 128 + half + j * 8) ^ swz] = *(const uint4*)&sk[j * 8];
            *(uint4*)&Vs[(e * 128 + half + j * 8) ^ swz] = *(const uint4*)&sv[j * 8];
        }
    }
    __syncthreads();

    const int lane = t & 63;
    const int w    = t >> 6;
    const int we   = w * 32;            // wave's e-rows
    const int col  = lane & 15;
    const int kgrp = (lane >> 4) * 8;
    const int fswz = col << 3;

    f32x4 acc[2][8];
    #pragma unroll
    for (int mi = 0; mi < 2; ++mi)
        #pragma unroll
        for (int ni = 0; ni < 8; ++ni)
            acc[mi][ni] = (f32x4){0.f, 0.f, 0.f, 0.f};

    #pragma unroll
    for (int kk = 0; kk < 4; ++kk) {
        const int kb = kk * 32 + kgrp;
        short8 af[2], bfv[8];
        #pragma unroll
        for (int mi = 0; mi < 2; ++mi)
            af[mi] = *(const short8*)&Ks[((we + mi * 16 + col) * 128 + kb) ^ fswz];
        #pragma unroll
        for (int ni = 0; ni < 8; ++ni)
            bfv[ni] = *(const short8*)&Vs[((ni * 16 + col) * 128 + kb) ^ fswz];
        #pragma unroll
        for (int mi = 0; mi < 2; ++mi)
            #pragma unroll
            for (int ni = 0; ni < 8; ++ni)
                acc[mi][ni] = __builtin_amdgcn_mfma_f32_16x16x32_bf16(
                    af[mi], bfv[ni], acc[mi][ni], 0, 0, 0);
    }

    __syncthreads();
    const int orow4 = (lane >> 4) * 4;
    #pragma unroll
    for (int mi = 0; mi < 2; ++mi)
        #pragma unroll
        for (int ni = 0; ni < 8; ++ni)
            #pragma unroll
            for (int j = 0; j < 4; ++j) {
                const int e = we + mi * 16 + orow4 + j;
                const int v = ni * 16 + col;
                Ks[(v * 128 + e) ^ ((v & 15) << 3)] = f2bf(acc[mi][ni][j]);
            }
    __syncthreads();

    ushort* P = part + (size_t)(b * 16 + c) * 16384;
    {
        const int v = t >> 1, half = (t & 1) * 64;
        const int swz = (v & 15) << 3;
        #pragma unroll
        for (int j = 0; j < 8; ++j)
            *(uint4*)&P[v * 128 + half + j * 8] =
                *(const uint4*)&Ks[(v * 128 + half + j * 8) ^ swz];
    }
}

// ---------------------------------------------------------------------------
// reduce: Mt[b][idx] = bf16(KSCALE * sum_{c<16} part[b*16+c][idx])
// Vectorized: 8 elems/thread via uint4 (was 1 elem, 16 scalar loads —
// Common-mistake #2). 16384 groups of 8 -> 64 blocks x 256 thr.
// ---------------------------------------------------------------------------
__global__ __launch_bounds__(256) void reduce_kernel(
    const ushort* __restrict__ part, ushort* __restrict__ Mt)
{
    const int g8 = blockIdx.x * 256 + threadIdx.x;   // 0..16383
    const int b = g8 >> 11;                          // /2048
    const int idx = (g8 & 2047) << 3;                // elem index, x8
    const ushort* P = part + (size_t)b * 16 * 16384 + idx;
    float s[8] = {0.f, 0.f, 0.f, 0.f, 0.f, 0.f, 0.f, 0.f};
    #pragma unroll
    for (int c = 0; c < 16; ++c) {
        uint4 u = *(const uint4*)&P[(size_t)c * 16384];
        const ushort* uw = (const ushort*)&u;
        #pragma unroll
        for (int j = 0; j < 8; ++j) s[j] += bf2f(uw[j]);
    }
    ushort tmp[8];
    #pragma unroll
    for (int j = 0; j < 8; ++j) tmp[j] = f2bf(s[j] * KSCALE);
    *(uint4*)&Mt[(size_t)b * 16384 + idx] = *(const uint4*)&tmp[0];
}

// ---------------------------------------------------------------------------
// qm: out[row][v] = sum_e qp[row][e] * Mt[b][v][e]
// ---------------------------------------------------------------------------
__global__ __launch_bounds__(256) void qm_kernel(
    const ushort* __restrict__ qp, const ushort* __restrict__ Mt,
    float* __restrict__ out)
{
    const int row0 = blockIdx.x * 64;
    const int b = row0 >> 11;
    const ushort* Q = qp + (size_t)row0 * 128;
    const ushort* M = Mt + (size_t)b * 16384;

    __shared__ __align__(16) ushort As[64 * 128];
    __shared__ __align__(16) ushort Bs[128 * 128];

    const int t = threadIdx.x;
    {
        const int r = t >> 2, cc = (t & 3) * 32;
        const int swz = (r & 15) << 3;
        #pragma unroll
        for (int j = 0; j < 4; ++j)
            *(uint4*)&As[(r * 128 + cc + j * 8) ^ swz] = *(const uint4*)&Q[r * 128 + cc + j * 8];
    }
    {
        const int r = t >> 1, cc = (t & 1) * 64;
        const int swz = (r & 15) << 3;
        #pragma unroll
        for (int j = 0; j < 8; ++j)
            *(uint4*)&Bs[(r * 128 + cc + j * 8) ^ swz] = *(const uint4*)&M[r * 128 + cc + j * 8];
    }
    __syncthreads();

    const int lane = t & 63;
    const int wcol = (t >> 6) * 32;
    const int col  = lane & 15;
    const int kgrp = (lane >> 4) * 8;
    const int fswz = col << 3;

    f32x4 acc[4][2];
    #pragma unroll
    for (int mi = 0; mi < 4; ++mi)
        #pragma unroll
        for (int ni = 0; ni < 2; ++ni)
            acc[mi][ni] = (f32x4){0.f, 0.f, 0.f, 0.f};

    #pragma unroll
    for (int kk = 0; kk < 4; ++kk) {
        const int kb = kk * 32 + kgrp;
        short8 af[4], bfv[2];
        #pragma unroll
        for (int mi = 0; mi < 4; ++mi)
            af[mi] = *(const short8*)&As[((mi * 16 + col) * 128 + kb) ^ fswz];
        #pragma unroll
        for (int ni = 0; ni < 2; ++ni)
            bfv[ni] = *(const short8*)&Bs[((wcol + ni * 16 + col) * 128 + kb) ^ fswz];
        #pragma unroll
        for (int mi = 0; mi < 4; ++mi)
            #pragma unroll
            for (int ni = 0; ni < 2; ++ni)
                acc[mi][ni] = __builtin_amdgcn_mfma_f32_16x16x32_bf16(
                    af[mi], bfv[ni], acc[mi][ni], 0, 0, 0);
    }

    const int orow = (lane >> 4) * 4;
    #pragma unroll
    for (int mi = 0; mi < 4; ++mi)
        #pragma unroll
        for (int ni = 0; ni < 2; ++ni)
            #pragma unroll
            for (int j = 0; j < 4; ++j)
                out[(size_t)(row0 + mi * 16 + orow + j) * 128 + wcol + ni * 16 + col] =
                    acc[mi][ni][j];
}

// ---------------------------------------------------------------------------
extern "C" void kernel_launch(void* const* d_in, const int* in_sizes, int n_in,
                              void* d_out, int out_size, void* d_ws, size_t ws_size,
                              hipStream_t stream)
{
    const float* query = (const float*)d_in[0];
    const float* key   = (const float*)d_in[1];
    const float* value = (const float*)d_in[2];
    const float* Wq    = (const float*)d_in[3];
    const float* bq    = (const float*)d_in[4];
    const float* Wk    = (const float*)d_in[5];
    const float* bk    = (const float*)d_in[6];
    const float* Wv    = (const float*)d_in[7];
    const float* bv    = (const float*)d_in[8];
    float* out = (float*)d_out;

    ushort* qp   = (ushort*)d_ws;                    // 16384*128 bf16
    ushort* kpT  = qp + (size_t)MROWS * 128;         // [128][16384] bf16
    ushort* vpT  = kpT + (size_t)MROWS * 128;        // [128][16384] bf16
    ushort* Wt   = vpT + (size_t)MROWS * 128;        // 3*128*1024 bf16
    ushort* part = Wt + (size_t)3 * 128 * 1024;      // 8*16*16384 bf16 (4 MB)
    ushort* Mt   = part + (size_t)8 * 16 * 16384;    // 8*16384 bf16

    prep_kernel<<<dim3(16, 2, 3), 256, 0, stream>>>(Wq, Wk, Wv, Wt);
    proj_kernel<<<dim3(256, 3), 512, 0, stream>>>(query, bq, key, bk, value, bv,
                                                  Wt, qp, kpT, vpT);
    ktv_kernel<<<dim3(16, NB), 256, 0, stream>>>(kpT, vpT, part);
    reduce_kernel<<<64, 256, 0, stream>>>(part, Mt);
    qm_kernel<<<MROWS / 64, 256, 0, stream>>>(qp, Mt, out);
}